// Round 9
// baseline (932.674 us; speedup 1.0000x reference)
//
#include <hip/hip_runtime.h>

#define LL 4096
#define NB 4
#define NC 64
#define NT 4
#define NLAYERS 10
#define XS 5120   // padded x row stride (in l units; x is [B][C][XS][4])
#define XPAD 512  // left/right zero pad (>= max dilation)

typedef float v2f __attribute__((ext_vector_type(2)));

// Constant-address-space cast: forces s_load for wave-uniform weight reads ->
// weights live in SGPRs, FMA is v_fmac_f32 acc, s_w, v_x (proven R6).
typedef __attribute__((address_space(4))) const float cfloat;
__device__ __forceinline__ cfloat* to_constant(const float* p) {
  return (cfloat*)(unsigned long long)p;
}

// ---------------- Threefry-2x32, key = (0, 42), 20 rounds ----------------
__device__ __forceinline__ void threefry2x32(unsigned x0, unsigned x1,
                                             unsigned& o0, unsigned& o1) {
  const unsigned ks0 = 0u, ks1 = 42u;
  const unsigned ks2 = 0x1BD11BDAu ^ ks0 ^ ks1;
  const unsigned ks[3] = {ks0, ks1, ks2};
  const unsigned r0[4] = {13u, 15u, 26u, 6u};
  const unsigned r1[4] = {17u, 29u, 16u, 24u};
  x0 += ks0; x1 += ks1;
#pragma unroll
  for (int g = 0; g < 5; ++g) {
    const unsigned* rr = (g & 1) ? r1 : r0;
#pragma unroll
    for (int j = 0; j < 4; ++j) {
      x0 += x1;
      unsigned r = rr[j];
      x1 = (x1 << r) | (x1 >> (32u - r));
      x1 ^= x0;
    }
    x0 += ks[(g + 1) % 3];
    x1 += ks[(g + 2) % 3] + (unsigned)(g + 1);
  }
  o0 = x0; o1 = x1;
}

__device__ __forceinline__ float u01(unsigned bits) {
  return __uint_as_float((bits >> 9) | 0x3f800000u) - 1.0f;
}

// LIF step: v = v + (x - v)/1.2 ; spike = v>=0.5 ; v *= (1-spike)
__device__ __forceinline__ float lif_step(float& v, float xt) {
  v = v + (xt - v) / 1.2f;
  float s = (v >= 0.5f) ? 1.0f : 0.0f;
  v = v * (1.0f - s);
  return s;
}

// ---------------- prep: transpose skip/res 1x1 + build wT ----------------
// skipT/resT: [i][c'][c]. wT: [i][g16][ci][k][col8], col<4 gate co=g*4+col,
// col>=4 filt co=64+g*4+col-4. (R6 layout.)
__global__ void prep_kernel(const float* __restrict__ skip_w,
                            const float* __restrict__ res_w,
                            const float* __restrict__ conv_w,
                            float* __restrict__ skipT,
                            float* __restrict__ resT,
                            float* __restrict__ wT) {
  int i = blockIdx.x;
  for (int idx = threadIdx.x; idx < 4096; idx += 256) {
    int c = idx >> 6, cp = idx & 63;
    skipT[i * 4096 + cp * 64 + c] = skip_w[i * 4096 + c * 64 + cp];
    resT[i * 4096 + cp * 64 + c] = res_w[i * 4096 + c * 64 + cp];
  }
  for (int idx = threadIdx.x; idx < 16 * 64 * 3 * 8; idx += 256) {
    int col = idx & 7;
    int r = idx >> 3;
    int k = r % 3; r /= 3;
    int ci = r % 64;
    int g = r / 64;  // 0..15
    int co = (col < 4) ? (g * 4 + col) : (64 + g * 4 + (col - 4));
    wT[i * 24576 + idx] = conv_w[(i * 128 + co) * 192 + ci * 3 + k];
  }
}

// ---------------- diffusion-step embedding -> proj[i][b][c] ----------------
__global__ void proj_kernel(const int* __restrict__ dstep,
                            const float* __restrict__ w1, const float* __restrict__ b1,
                            const float* __restrict__ w2, const float* __restrict__ b2,
                            const float* __restrict__ pw, const float* __restrict__ pb,
                            float* __restrict__ proj) {
  __shared__ float e1[NB][NC];
  __shared__ float e2[NB][NC];
  int i = blockIdx.x;
  int tid = threadIdx.x;
  int b = tid >> 6, c = tid & 63;
  float d = (float)dstep[b];
  float v = d * w1[i * 64 + c] + b1[i * 64 + c];
  v = v / (1.0f + expf(-v));  // silu
  e1[b][c] = v;
  __syncthreads();
  float a = b2[i * 64 + c];
  for (int cp = 0; cp < 64; ++cp) a += e1[b][cp] * w2[(i * 64 + c) * 64 + cp];
  e2[b][c] = a;
  __syncthreads();
  float p = pb[i * 64 + c];
  for (int cp = 0; cp < 64; ++cp) p += e2[b][cp] * pw[(i * 64 + c) * 64 + cp];
  proj[(i * 4 + b) * 64 + c] = p;
}

// ---------------- per-(layer,b,co) proj-weighted tap sums S0,S1,S2 ----------------
__global__ void pc_kernel(const float* __restrict__ proj,
                          const float* __restrict__ conv_w,
                          float* __restrict__ pc) {
  __shared__ float pv[64];
  int layer = blockIdx.x, b = blockIdx.y;
  int tid = threadIdx.x;  // 128
  if (tid < 64) pv[tid] = proj[(layer * 4 + b) * 64 + tid];
  __syncthreads();
  int co = tid;
  const float* w = conv_w + (layer * 128 + co) * 192;
  float s0 = 0.0f, s1 = 0.0f, s2 = 0.0f;
  for (int ci = 0; ci < 64; ++ci) {
    float p = pv[ci];
    s0 += p * w[ci * 3 + 0];
    s1 += p * w[ci * 3 + 1];
    s2 += p * w[ci * 3 + 2];
  }
  float* o = pc + ((layer * 4 + b) * 128 + co) * 3;
  o[0] = s0; o[1] = s1; o[2] = s2;
}

// ---------------- zero the pad margins of x (ws is poisoned every call) ---------
__global__ void padzero_kernel(float* __restrict__ x) {
  int row = blockIdx.x;  // 256 rows = B*C
  float* base = x + (size_t)row * XS * 4;
  for (int i = threadIdx.x; i < XPAD; i += 256) {
    *(float4*)&base[i * 4] = float4{0.f, 0.f, 0.f, 0.f};
    *(float4*)&base[(XPAD + LL + i) * 4] = float4{0.f, 0.f, 0.f, 0.f};
  }
}

// ---------------- Poisson encode + input conv + LIF -> x [B][C][XS][4] ---------
__global__ void encode_lif_kernel(const float* __restrict__ audio,
                                  const float* __restrict__ W_in,
                                  const float* __restrict__ b_in,
                                  float* __restrict__ x) {
  int tid = threadIdx.x;
  int lq = tid & 63, grp = tid >> 6;
  int l = blockIdx.x * 64 + lq;
  int b = blockIdx.y;
  float a = audio[b * LL + l];
  unsigned p0 = (unsigned)(b * LL + l);  // t=0 (o0), t=2 (o1)
  unsigned p1 = 16384u + p0;             // t=1 (o0), t=3 (o1)
  unsigned o00, o01, o10, o11;
  threefry2x32(p0, p0 + 32768u, o00, o01);
  threefry2x32(p1, p1 + 32768u, o10, o11);
  float sp[4];
  sp[0] = (u01(o00) < a) ? 1.0f : 0.0f;
  sp[1] = (u01(o10) < a) ? 1.0f : 0.0f;
  sp[2] = (u01(o01) < a) ? 1.0f : 0.0f;
  sp[3] = (u01(o11) < a) ? 1.0f : 0.0f;
  for (int j = 0; j < 16; ++j) {
    int c = grp * 16 + j;
    float w = W_in[c], bb = b_in[c];
    float v = 0.0f;
    float4 o;
    float* op = (float*)&o;
#pragma unroll
    for (int t = 0; t < 4; ++t) op[t] = lif_step(v, w * sp[t] + bb);
    *(float4*)&x[(size_t)((b * 64 + c) * XS + XPAD + l) * 4] = o;
  }
}

// ---------------- dilated conv + LIF + gate -> y [B][64][LL][4] ----------------
// grid (16, 16, 4), block 128 (2 waves): l-tile 256, co-group g (16 x
// (4 gate + 4 filt)), b. Thread: 2 CONSECUTIVE l, 4 t, 8 co.
// R6 structure kept exactly (SGPR weights via constant addr space, wA/wB
// double-buffer 1-ci ahead, x double-buffer 1-ci ahead); NEW: 2 l/thread —
// per-wave memory ILP doubles (6 x-loads in flight vs 3, 2 independent FMA
// chains), tap loads are contiguous 32B pairs, each SGPR weight serves 2x
// FMAs. Same 1024 blocks -> same 4 waves/SIMD. launch_bounds(128,4) caps
// VGPR at 128 (est ~124). Accumulation order (ci asc, k asc) -> bit-exact.
template <int DIL>
__global__ __launch_bounds__(128, 4) void layer_conv_kernel(
    const float* __restrict__ x, const float* __restrict__ wT,
    const float* __restrict__ conv_b, const float* __restrict__ pc,
    float* __restrict__ y, int layer) {
  int tid = threadIdx.x;  // 0..127
  int g = blockIdx.y;     // 0..15
  int b = blockIdx.z;
  int l = blockIdx.x * 256 + tid * 2;
  cfloat* cw = to_constant(wT + (size_t)(layer * 16 + g) * 1536);

  const float* px = x + (size_t)(b * 64 * XS + XPAD + l) * 4;  // ci=0 row

  float acc[8][8];  // [col][ll*4+t]; col 0-3 gate, 4-7 filt
#pragma unroll
  for (int j = 0; j < 8; ++j)
#pragma unroll
    for (int q = 0; q < 8; ++q) acc[j][q] = 0.0f;

  float4 xa[6], xb[6];      // [k*2+ll], 4 t each
  float wA[3][8], wB[3][8]; // [k][col] wave-uniform -> SGPRs

  auto loadx = [&](float4* dst) {
    const float* p0 = px - (size_t)DIL * 4;
    const float* p2 = px + (size_t)DIL * 4;
    dst[0] = *(const float4*)p0;
    dst[1] = *(const float4*)(p0 + 4);
    dst[2] = *(const float4*)px;
    dst[3] = *(const float4*)(px + 4);
    dst[4] = *(const float4*)p2;
    dst[5] = *(const float4*)(p2 + 4);
    px += (size_t)XS * 4;
  };
  auto loadw = [&](int ci, float (*w)[8]) {
#pragma unroll
    for (int k = 0; k < 3; ++k)
#pragma unroll
      for (int j = 0; j < 8; ++j)
        w[k][j] = cw[(ci * 3 + k) * 8 + j];  // s_load (merged)
  };
  auto compute = [&](const float (*w)[8], const float4* xv) {
#pragma unroll
    for (int k = 0; k < 3; ++k) {
#pragma unroll
      for (int ll = 0; ll < 2; ++ll) {
        const float* xk = (const float*)&xv[k * 2 + ll];
#pragma unroll
        for (int t = 0; t < 4; ++t) {
          float xq = xk[t];
#pragma unroll
          for (int j = 0; j < 8; ++j)
            acc[j][ll * 4 + t] += w[k][j] * xq;  // v_fmac_f32 acc, s, v
        }
      }
    }
  };

  loadx(xa);
  loadw(0, wA);
  for (int ci = 0; ci < 64; ci += 2) {
    loadx(xb);
    loadw(ci + 1, wB);
    compute(wA, xa);
    if (ci + 2 < 64) {
      loadx(xa);
      loadw(ci + 2, wA);
    }
    compute(wB, xb);
  }

  const float SIG1 = 0.73105857863000489f;   // sigmoid(1) fp32
  const float TANH1 = 0.76159415595576486f;  // tanh(1) fp32
  bool lb[2], rb[2];
  lb[0] = (l < DIL);     rb[0] = (l >= LL - DIL);
  lb[1] = (l + 1 < DIL); rb[1] = (l + 1 >= LL - DIL);
#pragma unroll
  for (int j = 0; j < 4; ++j) {
    int cog = g * 4 + j;
    int cof = 64 + g * 4 + j;
    const float* pg = pc + ((layer * 4 + b) * 128 + cog) * 3;
    const float* pf = pc + ((layer * 4 + b) * 128 + cof) * 3;
    float S0g = pg[0], S1g = pg[1], S2g = pg[2];
    float S0f = pf[0], S1f = pf[1], S2f = pf[2];
    float bg0 = conv_b[layer * 128 + cog] + S0g + S1g + S2g;
    float bf0 = conv_b[layer * 128 + cof] + S0f + S1f + S2f;
#pragma unroll
    for (int ll = 0; ll < 2; ++ll) {
      float bg = bg0 - (lb[ll] ? S0g : 0.0f) - (rb[ll] ? S2g : 0.0f);
      float bf = bf0 - (lb[ll] ? S0f : 0.0f) - (rb[ll] ? S2f : 0.0f);
      float vg = 0.0f, vf = 0.0f;
      float4 o;
      float* op = (float*)&o;
#pragma unroll
      for (int t = 0; t < 4; ++t) {
        float av = acc[j][ll * 4 + t];
        float fv = acc[j + 4][ll * 4 + t];
        float sg = lif_step(vg, av + bg);
        float sf = lif_step(vf, fv + bf);
        float gv = (sg != 0.0f) ? SIG1 : 0.5f;
        float tv = (sf != 0.0f) ? TANH1 : 0.0f;
        op[t] = gv * tv;
      }
      *(float4*)&y[(size_t)((b * 64 + cog) * LL + l + ll) * 4] = o;
    }
  }
}

// ---------------- 1x1 skip + res convs, MERGED ----------------
// grid (128, 4): l-tile 32, b. block 256. One block computes BOTH skip and
// res for its tile -> y tile read ONCE (y traffic halves vs split cv grid:
// 33.6 -> 16.8 MB/layer) at identical FMA-per-load intensity (4 float4 per
// 32 v2f). Thread: 4 c x 2 l x 4 t x {skip,res} (32 v2f acc). Per cp:
// skip-w float4 + res-w float4 + 2 y float4, prefetched 1 cp ahead.
// cp ascending = same summation order per output -> bit-exact.
__global__ __launch_bounds__(256) void skip_res_kernel(
    const float* __restrict__ y, const float* __restrict__ skipT,
    const float* __restrict__ resT, const float* __restrict__ skip_b,
    const float* __restrict__ res_b, float* __restrict__ tskip,
    float* __restrict__ x, int layer) {
  int tid = threadIdx.x;
  int lg = tid & 15;   // 16 l-groups of 2
  int cg = tid >> 4;   // 16 c-groups of 4
  int b = blockIdx.y;
  int l0 = blockIdx.x * 32 + lg * 2;
  int c0 = cg * 4;

  const float* ws_ = skipT + layer * 4096 + c0;  // [cp][c]
  const float* wr_ = resT + layer * 4096 + c0;
  const float* yb = y + (size_t)(b * 64 * LL + l0) * 4;

  v2f as_[16], ar_[16];  // [c4][l2][t-pair2]
#pragma unroll
  for (int q = 0; q < 16; ++q) {
    as_[q] = (v2f)(0.0f);
    ar_[q] = (v2f)(0.0f);
  }

  float4 wsa = *(const float4*)&ws_[0];
  float4 wra = *(const float4*)&wr_[0];
  float4 y0a = *(const float4*)yb;             // l0, t0..3
  float4 y1a = *(const float4*)(yb + 4);       // l0+1, t0..3

  for (int cp = 0; cp < 64; ++cp) {
    int cpn = (cp < 63) ? cp + 1 : 63;
    float4 wsb = *(const float4*)&ws_[cpn * 64];
    float4 wrb = *(const float4*)&wr_[cpn * 64];
    float4 y0b = *(const float4*)(yb + (size_t)cpn * LL * 4);
    float4 y1b = *(const float4*)(yb + (size_t)cpn * LL * 4 + 4);

    float wsv[4] = {wsa.x, wsa.y, wsa.z, wsa.w};
    float wrv[4] = {wra.x, wra.y, wra.z, wra.w};
    const v2f* yp0 = (const v2f*)&y0a;  // t01, t23
    const v2f* yp1 = (const v2f*)&y1a;
#pragma unroll
    for (int i = 0; i < 4; ++i) {
      v2f w2s, w2r;
      w2s.x = wsv[i]; w2s.y = wsv[i];
      w2r.x = wrv[i]; w2r.y = wrv[i];
      as_[i * 4 + 0] += w2s * yp0[0];
      as_[i * 4 + 1] += w2s * yp0[1];
      as_[i * 4 + 2] += w2s * yp1[0];
      as_[i * 4 + 3] += w2s * yp1[1];
      ar_[i * 4 + 0] += w2r * yp0[0];
      ar_[i * 4 + 1] += w2r * yp0[1];
      ar_[i * 4 + 2] += w2r * yp1[0];
      ar_[i * 4 + 3] += w2r * yp1[1];
    }
    wsa = wsb; wra = wrb; y0a = y0b; y1a = y1b;
  }

#pragma unroll
  for (int i = 0; i < 4; ++i) {
    int c = c0 + i;
    float sb = skip_b[layer * 64 + c];
    float rb = res_b[layer * 64 + c];
    // skip -> tskip RMW (l0, l0+1)
    {
      size_t idx = (size_t)((b * 64 + c) * LL + l0) * 4;
      float4 o0, o1;
      if (layer == 0) {
        o0 = float4{0.f, 0.f, 0.f, 0.f};
        o1 = o0;
      } else {
        o0 = *(const float4*)&tskip[idx];
        o1 = *(const float4*)&tskip[idx + 4];
      }
      o0.x += as_[i * 4 + 0][0] + sb;
      o0.y += as_[i * 4 + 0][1] + sb;
      o0.z += as_[i * 4 + 1][0] + sb;
      o0.w += as_[i * 4 + 1][1] + sb;
      o1.x += as_[i * 4 + 2][0] + sb;
      o1.y += as_[i * 4 + 2][1] + sb;
      o1.z += as_[i * 4 + 3][0] + sb;
      o1.w += as_[i * 4 + 3][1] + sb;
      *(float4*)&tskip[idx] = o0;
      *(float4*)&tskip[idx + 4] = o1;
    }
    // res -> x RMW (l0, l0+1)
    {
      size_t idx = (size_t)((b * 64 + c) * XS + XPAD + l0) * 4;
      float4 o0 = *(const float4*)&x[idx];
      float4 o1 = *(const float4*)&x[idx + 4];
      o0.x += ar_[i * 4 + 0][0] + rb;
      o0.y += ar_[i * 4 + 0][1] + rb;
      o0.z += ar_[i * 4 + 1][0] + rb;
      o0.w += ar_[i * 4 + 1][1] + rb;
      o1.x += ar_[i * 4 + 2][0] + rb;
      o1.y += ar_[i * 4 + 2][1] + rb;
      o1.z += ar_[i * 4 + 3][0] + rb;
      o1.w += ar_[i * 4 + 3][1] + rb;
      *(float4*)&x[idx] = o0;
      *(float4*)&x[idx + 4] = o1;
    }
  }
}

// ---------------- output conv + LIF + sum over T ----------------
__global__ void out_kernel(const float* __restrict__ tskip,
                           const float* __restrict__ W_out,
                           const float* __restrict__ b_out,
                           float* __restrict__ out) {
  __shared__ float red[4][4][64];  // [grp][t][lq]
  int tid = threadIdx.x;
  int lq = tid & 63, grp = tid >> 6;
  int l = blockIdx.x * 64 + lq;
  int b = blockIdx.y;
  float acc[4] = {0.0f, 0.0f, 0.0f, 0.0f};
  for (int j = 0; j < 16; ++j) {
    int c = grp * 16 + j;
    float w = W_out[c];
    float4 sv = *(const float4*)&tskip[(size_t)((b * 64 + c) * LL + l) * 4];
    acc[0] += fmaxf(sv.x, 0.0f) * w;
    acc[1] += fmaxf(sv.y, 0.0f) * w;
    acc[2] += fmaxf(sv.z, 0.0f) * w;
    acc[3] += fmaxf(sv.w, 0.0f) * w;
  }
#pragma unroll
  for (int t = 0; t < 4; ++t) red[grp][t][lq] = acc[t];
  __syncthreads();
  if (grp == 0) {
    float bo = b_out[0];
    float v = 0.0f, s = 0.0f;
#pragma unroll
    for (int t = 0; t < 4; ++t) {
      float a = red[0][t][lq] + red[1][t][lq] + red[2][t][lq] + red[3][t][lq] + bo;
      s += lif_step(v, a);
    }
    out[b * LL + l] = s;
  }
}

extern "C" void kernel_launch(void* const* d_in, const int* in_sizes, int n_in,
                              void* d_out, int out_size, void* d_ws, size_t ws_size,
                              hipStream_t stream) {
  const float* audio   = (const float*)d_in[0];
  const int*   dstep   = (const int*)d_in[1];
  const float* W_in    = (const float*)d_in[2];
  const float* b_in    = (const float*)d_in[3];
  const float* demb_w1 = (const float*)d_in[4];
  const float* demb_b1 = (const float*)d_in[5];
  const float* demb_w2 = (const float*)d_in[6];
  const float* demb_b2 = (const float*)d_in[7];
  const float* dproj_w = (const float*)d_in[8];
  const float* dproj_b = (const float*)d_in[9];
  const float* conv_w  = (const float*)d_in[10];
  const float* conv_b  = (const float*)d_in[11];
  const float* skip_w  = (const float*)d_in[12];
  const float* skip_b  = (const float*)d_in[13];
  const float* res_w   = (const float*)d_in[14];
  const float* res_b   = (const float*)d_in[15];
  const float* W_out   = (const float*)d_in[16];
  const float* b_out   = (const float*)d_in[17];
  float* out = (float*)d_out;
  float* ws = (float*)d_ws;

  float* proj  = ws;                   // 2560
  float* skipT = proj + 2560;          // 40960
  float* resT  = skipT + 40960;        // 40960
  float* pc    = resT + 40960;         // 15360
  float* wT    = pc + 15360;           // 10*16*64*24 = 245760
  float* x     = wT + 245760;          // 4*64*5120*4 = 5242880
  float* y     = x + 5242880;          // 4*64*4096*4 = 4194304
  float* tskip = y + 4194304;          // 4194304

  prep_kernel<<<10, 256, 0, stream>>>(skip_w, res_w, conv_w, skipT, resT, wT);
  proj_kernel<<<10, 256, 0, stream>>>(dstep, demb_w1, demb_b1, demb_w2, demb_b2,
                                      dproj_w, dproj_b, proj);
  pc_kernel<<<dim3(10, 4), 128, 0, stream>>>(proj, conv_w, pc);
  padzero_kernel<<<256, 256, 0, stream>>>(x);
  encode_lif_kernel<<<dim3(64, 4), 256, 0, stream>>>(audio, W_in, b_in, x);

  for (int i = 0; i < NLAYERS; ++i) {
    dim3 gc(16, 16, 4);
    switch (i) {
      case 0: layer_conv_kernel<1><<<gc, 128, 0, stream>>>(x, wT, conv_b, pc, y, i); break;
      case 1: layer_conv_kernel<2><<<gc, 128, 0, stream>>>(x, wT, conv_b, pc, y, i); break;
      case 2: layer_conv_kernel<4><<<gc, 128, 0, stream>>>(x, wT, conv_b, pc, y, i); break;
      case 3: layer_conv_kernel<8><<<gc, 128, 0, stream>>>(x, wT, conv_b, pc, y, i); break;
      case 4: layer_conv_kernel<16><<<gc, 128, 0, stream>>>(x, wT, conv_b, pc, y, i); break;
      case 5: layer_conv_kernel<32><<<gc, 128, 0, stream>>>(x, wT, conv_b, pc, y, i); break;
      case 6: layer_conv_kernel<64><<<gc, 128, 0, stream>>>(x, wT, conv_b, pc, y, i); break;
      case 7: layer_conv_kernel<128><<<gc, 128, 0, stream>>>(x, wT, conv_b, pc, y, i); break;
      case 8: layer_conv_kernel<256><<<gc, 128, 0, stream>>>(x, wT, conv_b, pc, y, i); break;
      case 9: layer_conv_kernel<512><<<gc, 128, 0, stream>>>(x, wT, conv_b, pc, y, i); break;
    }
    skip_res_kernel<<<dim3(128, 4), 256, 0, stream>>>(y, skipT, resT, skip_b,
                                                      res_b, tskip, x, i);
  }
  out_kernel<<<dim3(64, 4), 256, 0, stream>>>(tskip, W_out, b_out, out);
}

// Round 10
// 795.967 us; speedup vs baseline: 1.1717x; 1.1717x over previous
//
#include <hip/hip_runtime.h>

#define LL 4096
#define NB 4
#define NC 64
#define NT 4
#define NLAYERS 10
#define XS 5120   // padded x row stride (in l units; x is [B][C][XS][4])
#define XPAD 512  // left/right zero pad (>= max dilation)

typedef float v2f __attribute__((ext_vector_type(2)));

// Constant-address-space cast: forces s_load for wave-uniform weight reads ->
// weights live in SGPRs, FMA is v_fmac_f32 acc, s_w, v_x (proven R6: 47.4us).
typedef __attribute__((address_space(4))) const float cfloat;
__device__ __forceinline__ cfloat* to_constant(const float* p) {
  return (cfloat*)(unsigned long long)p;
}

// ---------------- Threefry-2x32, key = (0, 42), 20 rounds ----------------
__device__ __forceinline__ void threefry2x32(unsigned x0, unsigned x1,
                                             unsigned& o0, unsigned& o1) {
  const unsigned ks0 = 0u, ks1 = 42u;
  const unsigned ks2 = 0x1BD11BDAu ^ ks0 ^ ks1;
  const unsigned ks[3] = {ks0, ks1, ks2};
  const unsigned r0[4] = {13u, 15u, 26u, 6u};
  const unsigned r1[4] = {17u, 29u, 16u, 24u};
  x0 += ks0; x1 += ks1;
#pragma unroll
  for (int g = 0; g < 5; ++g) {
    const unsigned* rr = (g & 1) ? r1 : r0;
#pragma unroll
    for (int j = 0; j < 4; ++j) {
      x0 += x1;
      unsigned r = rr[j];
      x1 = (x1 << r) | (x1 >> (32u - r));
      x1 ^= x0;
    }
    x0 += ks[(g + 1) % 3];
    x1 += ks[(g + 2) % 3] + (unsigned)(g + 1);
  }
  o0 = x0; o1 = x1;
}

__device__ __forceinline__ float u01(unsigned bits) {
  return __uint_as_float((bits >> 9) | 0x3f800000u) - 1.0f;
}

// LIF step: v = v + (x - v)/1.2 ; spike = v>=0.5 ; v *= (1-spike)
__device__ __forceinline__ float lif_step(float& v, float xt) {
  v = v + (xt - v) / 1.2f;
  float s = (v >= 0.5f) ? 1.0f : 0.0f;
  v = v * (1.0f - s);
  return s;
}

// ---------------- prep: transpose skip/res 1x1 + build wT ----------------
// skipT/resT: [i][c'][c]. wT: [i][g16][ci][k][col8], col<4 gate co=g*4+col,
// col>=4 filt co=64+g*4+col-4. (R6 layout.)
__global__ void prep_kernel(const float* __restrict__ skip_w,
                            const float* __restrict__ res_w,
                            const float* __restrict__ conv_w,
                            float* __restrict__ skipT,
                            float* __restrict__ resT,
                            float* __restrict__ wT) {
  int i = blockIdx.x;
  for (int idx = threadIdx.x; idx < 4096; idx += 256) {
    int c = idx >> 6, cp = idx & 63;
    skipT[i * 4096 + cp * 64 + c] = skip_w[i * 4096 + c * 64 + cp];
    resT[i * 4096 + cp * 64 + c] = res_w[i * 4096 + c * 64 + cp];
  }
  for (int idx = threadIdx.x; idx < 16 * 64 * 3 * 8; idx += 256) {
    int col = idx & 7;
    int r = idx >> 3;
    int k = r % 3; r /= 3;
    int ci = r % 64;
    int g = r / 64;  // 0..15
    int co = (col < 4) ? (g * 4 + col) : (64 + g * 4 + (col - 4));
    wT[i * 24576 + idx] = conv_w[(i * 128 + co) * 192 + ci * 3 + k];
  }
}

// ---------------- diffusion-step embedding -> proj[i][b][c] ----------------
__global__ void proj_kernel(const int* __restrict__ dstep,
                            const float* __restrict__ w1, const float* __restrict__ b1,
                            const float* __restrict__ w2, const float* __restrict__ b2,
                            const float* __restrict__ pw, const float* __restrict__ pb,
                            float* __restrict__ proj) {
  __shared__ float e1[NB][NC];
  __shared__ float e2[NB][NC];
  int i = blockIdx.x;
  int tid = threadIdx.x;
  int b = tid >> 6, c = tid & 63;
  float d = (float)dstep[b];
  float v = d * w1[i * 64 + c] + b1[i * 64 + c];
  v = v / (1.0f + expf(-v));  // silu
  e1[b][c] = v;
  __syncthreads();
  float a = b2[i * 64 + c];
  for (int cp = 0; cp < 64; ++cp) a += e1[b][cp] * w2[(i * 64 + c) * 64 + cp];
  e2[b][c] = a;
  __syncthreads();
  float p = pb[i * 64 + c];
  for (int cp = 0; cp < 64; ++cp) p += e2[b][cp] * pw[(i * 64 + c) * 64 + cp];
  proj[(i * 4 + b) * 64 + c] = p;
}

// ---------------- per-(layer,b,co) proj-weighted tap sums S0,S1,S2 ----------------
__global__ void pc_kernel(const float* __restrict__ proj,
                          const float* __restrict__ conv_w,
                          float* __restrict__ pc) {
  __shared__ float pv[64];
  int layer = blockIdx.x, b = blockIdx.y;
  int tid = threadIdx.x;  // 128
  if (tid < 64) pv[tid] = proj[(layer * 4 + b) * 64 + tid];
  __syncthreads();
  int co = tid;
  const float* w = conv_w + (layer * 128 + co) * 192;
  float s0 = 0.0f, s1 = 0.0f, s2 = 0.0f;
  for (int ci = 0; ci < 64; ++ci) {
    float p = pv[ci];
    s0 += p * w[ci * 3 + 0];
    s1 += p * w[ci * 3 + 1];
    s2 += p * w[ci * 3 + 2];
  }
  float* o = pc + ((layer * 4 + b) * 128 + co) * 3;
  o[0] = s0; o[1] = s1; o[2] = s2;
}

// ---------------- zero the pad margins of x (ws is poisoned every call) ---------
__global__ void padzero_kernel(float* __restrict__ x) {
  int row = blockIdx.x;  // 256 rows = B*C
  float* base = x + (size_t)row * XS * 4;
  for (int i = threadIdx.x; i < XPAD; i += 256) {
    *(float4*)&base[i * 4] = float4{0.f, 0.f, 0.f, 0.f};
    *(float4*)&base[(XPAD + LL + i) * 4] = float4{0.f, 0.f, 0.f, 0.f};
  }
}

// ---------------- Poisson encode + input conv + LIF -> x [B][C][XS][4] ---------
__global__ void encode_lif_kernel(const float* __restrict__ audio,
                                  const float* __restrict__ W_in,
                                  const float* __restrict__ b_in,
                                  float* __restrict__ x) {
  int tid = threadIdx.x;
  int lq = tid & 63, grp = tid >> 6;
  int l = blockIdx.x * 64 + lq;
  int b = blockIdx.y;
  float a = audio[b * LL + l];
  unsigned p0 = (unsigned)(b * LL + l);  // t=0 (o0), t=2 (o1)
  unsigned p1 = 16384u + p0;             // t=1 (o0), t=3 (o1)
  unsigned o00, o01, o10, o11;
  threefry2x32(p0, p0 + 32768u, o00, o01);
  threefry2x32(p1, p1 + 32768u, o10, o11);
  float sp[4];
  sp[0] = (u01(o00) < a) ? 1.0f : 0.0f;
  sp[1] = (u01(o10) < a) ? 1.0f : 0.0f;
  sp[2] = (u01(o01) < a) ? 1.0f : 0.0f;
  sp[3] = (u01(o11) < a) ? 1.0f : 0.0f;
  for (int j = 0; j < 16; ++j) {
    int c = grp * 16 + j;
    float w = W_in[c], bb = b_in[c];
    float v = 0.0f;
    float4 o;
    float* op = (float*)&o;
#pragma unroll
    for (int t = 0; t < 4; ++t) op[t] = lif_step(v, w * sp[t] + bb);
    *(float4*)&x[(size_t)((b * 64 + c) * XS + XPAD + l) * 4] = o;
  }
}

// ---------------- dilated conv + LIF + gate -> y [B][64][LL][4] ----------------
// EXACT R6 kernel (proven 47.4us; every perturbation in R7/R8/R9 regressed).
// grid (16, 16, 4), block 256: l-tile 256, co-group g (16 x (4 gate +
// 4 filt)), b. Thread: 1 l, 4 t, 8 co; acc[8][4] scalar f32. Weights
// wave-uniform -> s_load/SGPR (constant addr space), wA/wB double-buffer
// 1 ci ahead; x float4 double-buffer 1 ci ahead.
// Accumulation order (ci asc, k asc) -> bit-exact.
template <int DIL>
__global__ __launch_bounds__(256) void layer_conv_kernel(
    const float* __restrict__ x, const float* __restrict__ wT,
    const float* __restrict__ conv_b, const float* __restrict__ pc,
    float* __restrict__ y, int layer) {
  int tid = threadIdx.x;
  int g = blockIdx.y;   // 0..15
  int b = blockIdx.z;
  int l = blockIdx.x * 256 + tid;
  cfloat* cw = to_constant(wT + (size_t)(layer * 16 + g) * 1536);

  const float* px = x + (size_t)(b * 64 * XS + XPAD + l) * 4;  // ci=0 row

  float acc[8][4];  // [col][t]; col 0-3 gate, 4-7 filt
#pragma unroll
  for (int j = 0; j < 8; ++j)
#pragma unroll
    for (int t = 0; t < 4; ++t) acc[j][t] = 0.0f;

  float4 xa[3], xb[3];      // [k] = 4 t values
  float wA[3][8], wB[3][8]; // [k][col] wave-uniform -> SGPRs

  auto loadx = [&](float4* dst) {
    dst[0] = *(const float4*)(px - (size_t)DIL * 4);
    dst[1] = *(const float4*)px;
    dst[2] = *(const float4*)(px + (size_t)DIL * 4);
    px += (size_t)XS * 4;
  };
  auto loadw = [&](int ci, float (*w)[8]) {
#pragma unroll
    for (int k = 0; k < 3; ++k)
#pragma unroll
      for (int j = 0; j < 8; ++j)
        w[k][j] = cw[(ci * 3 + k) * 8 + j];  // s_load (merged)
  };
  auto compute = [&](const float (*w)[8], const float4* xv) {
#pragma unroll
    for (int k = 0; k < 3; ++k) {
      const float* xk = (const float*)&xv[k];
#pragma unroll
      for (int t = 0; t < 4; ++t) {
        float xq = xk[t];
#pragma unroll
        for (int j = 0; j < 8; ++j)
          acc[j][t] += w[k][j] * xq;  // v_fmac_f32 acc, s, v
      }
    }
  };

  loadx(xa);
  loadw(0, wA);
  for (int ci = 0; ci < 64; ci += 2) {
    loadx(xb);
    loadw(ci + 1, wB);
    compute(wA, xa);
    if (ci + 2 < 64) {
      loadx(xa);
      loadw(ci + 2, wA);
    }
    compute(wB, xb);
  }

  const float SIG1 = 0.73105857863000489f;   // sigmoid(1) fp32
  const float TANH1 = 0.76159415595576486f;  // tanh(1) fp32
  bool lb = (l < DIL), rb = (l >= LL - DIL);
#pragma unroll
  for (int j = 0; j < 4; ++j) {
    int cog = g * 4 + j;
    int cof = 64 + g * 4 + j;
    const float* pg = pc + ((layer * 4 + b) * 128 + cog) * 3;
    const float* pf = pc + ((layer * 4 + b) * 128 + cof) * 3;
    float S0g = pg[0], S1g = pg[1], S2g = pg[2];
    float S0f = pf[0], S1f = pf[1], S2f = pf[2];
    float bg = conv_b[layer * 128 + cog] + S0g + S1g + S2g;
    float bf = conv_b[layer * 128 + cof] + S0f + S1f + S2f;
    bg -= (lb ? S0g : 0.0f) + (rb ? S2g : 0.0f);
    bf -= (lb ? S0f : 0.0f) + (rb ? S2f : 0.0f);
    float vg = 0.0f, vf = 0.0f;
    float4 o;
    float* op = (float*)&o;
#pragma unroll
    for (int t = 0; t < 4; ++t) {
      float av = acc[j][t];
      float fv = acc[j + 4][t];
      float sg = lif_step(vg, av + bg);
      float sf = lif_step(vf, fv + bf);
      float gv = (sg != 0.0f) ? SIG1 : 0.5f;
      float tv = (sf != 0.0f) ? TANH1 : 0.0f;
      op[t] = gv * tv;
    }
    *(float4*)&y[(size_t)((b * 64 + cog) * LL + l) * 4] = o;
  }
}

// ---------------- 1x1 skip + res convs, MERGED (proven R9: ~20us/layer) ----
// grid (128, 4): l-tile 32, b. block 256. One block computes BOTH skip and
// res for its tile -> y tile read ONCE (y traffic halved vs split cv grid).
// Thread: 4 c x 2 l x 4 t x {skip,res} (32 v2f acc). Per cp: skip-w float4
// + res-w float4 + 2 y float4, prefetched 1 cp ahead. cp ascending = same
// summation order per output -> bit-exact.
__global__ __launch_bounds__(256) void skip_res_kernel(
    const float* __restrict__ y, const float* __restrict__ skipT,
    const float* __restrict__ resT, const float* __restrict__ skip_b,
    const float* __restrict__ res_b, float* __restrict__ tskip,
    float* __restrict__ x, int layer) {
  int tid = threadIdx.x;
  int lg = tid & 15;   // 16 l-groups of 2
  int cg = tid >> 4;   // 16 c-groups of 4
  int b = blockIdx.y;
  int l0 = blockIdx.x * 32 + lg * 2;
  int c0 = cg * 4;

  const float* ws_ = skipT + layer * 4096 + c0;  // [cp][c]
  const float* wr_ = resT + layer * 4096 + c0;
  const float* yb = y + (size_t)(b * 64 * LL + l0) * 4;

  v2f as_[16], ar_[16];  // [c4][l2][t-pair2]
#pragma unroll
  for (int q = 0; q < 16; ++q) {
    as_[q] = (v2f)(0.0f);
    ar_[q] = (v2f)(0.0f);
  }

  float4 wsa = *(const float4*)&ws_[0];
  float4 wra = *(const float4*)&wr_[0];
  float4 y0a = *(const float4*)yb;             // l0, t0..3
  float4 y1a = *(const float4*)(yb + 4);       // l0+1, t0..3

  for (int cp = 0; cp < 64; ++cp) {
    int cpn = (cp < 63) ? cp + 1 : 63;
    float4 wsb = *(const float4*)&ws_[cpn * 64];
    float4 wrb = *(const float4*)&wr_[cpn * 64];
    float4 y0b = *(const float4*)(yb + (size_t)cpn * LL * 4);
    float4 y1b = *(const float4*)(yb + (size_t)cpn * LL * 4 + 4);

    float wsv[4] = {wsa.x, wsa.y, wsa.z, wsa.w};
    float wrv[4] = {wra.x, wra.y, wra.z, wra.w};
    const v2f* yp0 = (const v2f*)&y0a;  // t01, t23
    const v2f* yp1 = (const v2f*)&y1a;
#pragma unroll
    for (int i = 0; i < 4; ++i) {
      v2f w2s, w2r;
      w2s.x = wsv[i]; w2s.y = wsv[i];
      w2r.x = wrv[i]; w2r.y = wrv[i];
      as_[i * 4 + 0] += w2s * yp0[0];
      as_[i * 4 + 1] += w2s * yp0[1];
      as_[i * 4 + 2] += w2s * yp1[0];
      as_[i * 4 + 3] += w2s * yp1[1];
      ar_[i * 4 + 0] += w2r * yp0[0];
      ar_[i * 4 + 1] += w2r * yp0[1];
      ar_[i * 4 + 2] += w2r * yp1[0];
      ar_[i * 4 + 3] += w2r * yp1[1];
    }
    wsa = wsb; wra = wrb; y0a = y0b; y1a = y1b;
  }

#pragma unroll
  for (int i = 0; i < 4; ++i) {
    int c = c0 + i;
    float sb = skip_b[layer * 64 + c];
    float rb = res_b[layer * 64 + c];
    // skip -> tskip RMW (l0, l0+1)
    {
      size_t idx = (size_t)((b * 64 + c) * LL + l0) * 4;
      float4 o0, o1;
      if (layer == 0) {
        o0 = float4{0.f, 0.f, 0.f, 0.f};
        o1 = o0;
      } else {
        o0 = *(const float4*)&tskip[idx];
        o1 = *(const float4*)&tskip[idx + 4];
      }
      o0.x += as_[i * 4 + 0][0] + sb;
      o0.y += as_[i * 4 + 0][1] + sb;
      o0.z += as_[i * 4 + 1][0] + sb;
      o0.w += as_[i * 4 + 1][1] + sb;
      o1.x += as_[i * 4 + 2][0] + sb;
      o1.y += as_[i * 4 + 2][1] + sb;
      o1.z += as_[i * 4 + 3][0] + sb;
      o1.w += as_[i * 4 + 3][1] + sb;
      *(float4*)&tskip[idx] = o0;
      *(float4*)&tskip[idx + 4] = o1;
    }
    // res -> x RMW (l0, l0+1)
    {
      size_t idx = (size_t)((b * 64 + c) * XS + XPAD + l0) * 4;
      float4 o0 = *(const float4*)&x[idx];
      float4 o1 = *(const float4*)&x[idx + 4];
      o0.x += ar_[i * 4 + 0][0] + rb;
      o0.y += ar_[i * 4 + 0][1] + rb;
      o0.z += ar_[i * 4 + 1][0] + rb;
      o0.w += ar_[i * 4 + 1][1] + rb;
      o1.x += ar_[i * 4 + 2][0] + rb;
      o1.y += ar_[i * 4 + 2][1] + rb;
      o1.z += ar_[i * 4 + 3][0] + rb;
      o1.w += ar_[i * 4 + 3][1] + rb;
      *(float4*)&x[idx] = o0;
      *(float4*)&x[idx + 4] = o1;
    }
  }
}

// ---------------- output conv + LIF + sum over T ----------------
__global__ void out_kernel(const float* __restrict__ tskip,
                           const float* __restrict__ W_out,
                           const float* __restrict__ b_out,
                           float* __restrict__ out) {
  __shared__ float red[4][4][64];  // [grp][t][lq]
  int tid = threadIdx.x;
  int lq = tid & 63, grp = tid >> 6;
  int l = blockIdx.x * 64 + lq;
  int b = blockIdx.y;
  float acc[4] = {0.0f, 0.0f, 0.0f, 0.0f};
  for (int j = 0; j < 16; ++j) {
    int c = grp * 16 + j;
    float w = W_out[c];
    float4 sv = *(const float4*)&tskip[(size_t)((b * 64 + c) * LL + l) * 4];
    acc[0] += fmaxf(sv.x, 0.0f) * w;
    acc[1] += fmaxf(sv.y, 0.0f) * w;
    acc[2] += fmaxf(sv.z, 0.0f) * w;
    acc[3] += fmaxf(sv.w, 0.0f) * w;
  }
#pragma unroll
  for (int t = 0; t < 4; ++t) red[grp][t][lq] = acc[t];
  __syncthreads();
  if (grp == 0) {
    float bo = b_out[0];
    float v = 0.0f, s = 0.0f;
#pragma unroll
    for (int t = 0; t < 4; ++t) {
      float a = red[0][t][lq] + red[1][t][lq] + red[2][t][lq] + red[3][t][lq] + bo;
      s += lif_step(v, a);
    }
    out[b * LL + l] = s;
  }
}

extern "C" void kernel_launch(void* const* d_in, const int* in_sizes, int n_in,
                              void* d_out, int out_size, void* d_ws, size_t ws_size,
                              hipStream_t stream) {
  const float* audio   = (const float*)d_in[0];
  const int*   dstep   = (const int*)d_in[1];
  const float* W_in    = (const float*)d_in[2];
  const float* b_in    = (const float*)d_in[3];
  const float* demb_w1 = (const float*)d_in[4];
  const float* demb_b1 = (const float*)d_in[5];
  const float* demb_w2 = (const float*)d_in[6];
  const float* demb_b2 = (const float*)d_in[7];
  const float* dproj_w = (const float*)d_in[8];
  const float* dproj_b = (const float*)d_in[9];
  const float* conv_w  = (const float*)d_in[10];
  const float* conv_b  = (const float*)d_in[11];
  const float* skip_w  = (const float*)d_in[12];
  const float* skip_b  = (const float*)d_in[13];
  const float* res_w   = (const float*)d_in[14];
  const float* res_b   = (const float*)d_in[15];
  const float* W_out   = (const float*)d_in[16];
  const float* b_out   = (const float*)d_in[17];
  float* out = (float*)d_out;
  float* ws = (float*)d_ws;

  float* proj  = ws;                   // 2560
  float* skipT = proj + 2560;          // 40960
  float* resT  = skipT + 40960;        // 40960
  float* pc    = resT + 40960;         // 15360
  float* wT    = pc + 15360;           // 10*16*64*24 = 245760
  float* x     = wT + 245760;          // 4*64*5120*4 = 5242880
  float* y     = x + 5242880;          // 4*64*4096*4 = 4194304
  float* tskip = y + 4194304;          // 4194304

  prep_kernel<<<10, 256, 0, stream>>>(skip_w, res_w, conv_w, skipT, resT, wT);
  proj_kernel<<<10, 256, 0, stream>>>(dstep, demb_w1, demb_b1, demb_w2, demb_b2,
                                      dproj_w, dproj_b, proj);
  pc_kernel<<<dim3(10, 4), 128, 0, stream>>>(proj, conv_w, pc);
  padzero_kernel<<<256, 256, 0, stream>>>(x);
  encode_lif_kernel<<<dim3(64, 4), 256, 0, stream>>>(audio, W_in, b_in, x);

  for (int i = 0; i < NLAYERS; ++i) {
    dim3 gc(16, 16, 4);
    switch (i) {
      case 0: layer_conv_kernel<1><<<gc, 256, 0, stream>>>(x, wT, conv_b, pc, y, i); break;
      case 1: layer_conv_kernel<2><<<gc, 256, 0, stream>>>(x, wT, conv_b, pc, y, i); break;
      case 2: layer_conv_kernel<4><<<gc, 256, 0, stream>>>(x, wT, conv_b, pc, y, i); break;
      case 3: layer_conv_kernel<8><<<gc, 256, 0, stream>>>(x, wT, conv_b, pc, y, i); break;
      case 4: layer_conv_kernel<16><<<gc, 256, 0, stream>>>(x, wT, conv_b, pc, y, i); break;
      case 5: layer_conv_kernel<32><<<gc, 256, 0, stream>>>(x, wT, conv_b, pc, y, i); break;
      case 6: layer_conv_kernel<64><<<gc, 256, 0, stream>>>(x, wT, conv_b, pc, y, i); break;
      case 7: layer_conv_kernel<128><<<gc, 256, 0, stream>>>(x, wT, conv_b, pc, y, i); break;
      case 8: layer_conv_kernel<256><<<gc, 256, 0, stream>>>(x, wT, conv_b, pc, y, i); break;
      case 9: layer_conv_kernel<512><<<gc, 256, 0, stream>>>(x, wT, conv_b, pc, y, i); break;
    }
    skip_res_kernel<<<dim3(128, 4), 256, 0, stream>>>(y, skipT, resT, skip_b,
                                                      res_b, tskip, x, i);
  }
  out_kernel<<<dim3(64, 4), 256, 0, stream>>>(tskip, W_out, b_out, out);
}